// Round 5
// baseline (621.706 us; speedup 1.0000x reference)
//
#include <hip/hip_runtime.h>
#include <hip/hip_fp16.h>

#define NN 100000      // nodes
#define NE 1600000     // edges
#define INF 32
#define HF 32
#define CF 8

#define BNODE 256                        // nodes per bucket
#define NBKT ((NN + BNODE - 1) / BNODE)  // 391
#define CAP 4608                         // slots/bucket: mean 4092, sigma 64 -> +8 sigma
#define CHUNK 2048                       // edges per bin block
#define NBLK_BIN ((NE + CHUNK - 1) / CHUNK)  // 782
#define SPLIT 2                          // edge-slices per bucket

// ---------------- K1: degree histograms (int atomics, high occupancy) ----------------
__global__ void deg_kernel(const int* __restrict__ src, const int* __restrict__ dst,
                           int* __restrict__ deg_out, int* __restrict__ deg_in) {
    int e = blockIdx.x * blockDim.x + threadIdx.x;
    if (e < NE) {
        atomicAdd(&deg_out[src[e]], 1);
        atomicAdd(&deg_in[dst[e]], 1);
    }
}

// ---------------- K2: h = (x @ W1) * rsqrt(deg_out), packed f16 pairs ----------------
__global__ void xw1_kernel(const float* __restrict__ x, const float* __restrict__ W1,
                           const int* __restrict__ deg_out, unsigned int* __restrict__ h) {
    __shared__ float w[INF * HF];
    for (int i = threadIdx.x; i < INF * HF; i += blockDim.x) w[i] = W1[i];
    __syncthreads();
    int n = blockIdx.x * blockDim.x + threadIdx.x;
    if (n >= NN) return;

    float xr[INF];
    const float4* xp = (const float4*)(x + (size_t)n * INF);
    #pragma unroll
    for (int i = 0; i < INF / 4; ++i) {
        float4 v = xp[i];
        xr[4*i+0] = v.x; xr[4*i+1] = v.y; xr[4*i+2] = v.z; xr[4*i+3] = v.w;
    }
    float acc[HF];
    #pragma unroll
    for (int c = 0; c < HF; ++c) acc[c] = 0.0f;
    #pragma unroll
    for (int k = 0; k < INF; ++k) {
        float xv = xr[k];
        #pragma unroll
        for (int c = 0; c < HF; ++c) acc[c] = fmaf(xv, w[k * HF + c], acc[c]);
    }
    float rs = rsqrtf(fmaxf((float)deg_out[n], 1.0f));
    unsigned int pk[HF / 2];
    #pragma unroll
    for (int i = 0; i < HF / 2; ++i) {
        __half2 p = __floats2half2_rn(acc[2*i] * rs, acc[2*i+1] * rs);
        pk[i] = *(unsigned int*)&p;
    }
    uint4* hp = (uint4*)(h + (size_t)n * (HF / 2));
    #pragma unroll
    for (int i = 0; i < 4; ++i) {
        uint4 v;
        v.x = pk[4*i+0]; v.y = pk[4*i+1]; v.z = pk[4*i+2]; v.w = pk[4*i+3];
        hp[i] = v;
    }
}

// ---------------- K3: bin edges by dst bucket ----------------
// payload = (dst & 255) << 17 | src   (src < 2^17)
__global__ void __launch_bounds__(256) bin_kernel(
        const int* __restrict__ src, const int* __restrict__ dst,
        int* __restrict__ gcur, unsigned int* __restrict__ bins) {
    __shared__ int cnt[NBKT];
    __shared__ int base[NBKT];
    for (int i = threadIdx.x; i < NBKT; i += 256) cnt[i] = 0;
    __syncthreads();
    int e0 = blockIdx.x * CHUNK;
    int e1 = min(e0 + CHUNK, NE);
    for (int e = e0 + threadIdx.x; e < e1; e += 256)
        atomicAdd(&cnt[dst[e] >> 8], 1);
    __syncthreads();
    for (int i = threadIdx.x; i < NBKT; i += 256) {
        base[i] = atomicAdd(&gcur[i], cnt[i]);
        cnt[i] = 0;
    }
    __syncthreads();
    for (int e = e0 + threadIdx.x; e < e1; e += 256) {
        int d = dst[e], s = src[e];
        int b = d >> 8;
        int off = base[b] + atomicAdd(&cnt[b], 1);
        if (off < CAP)
            bins[(size_t)b * CAP + off] = ((unsigned)(d & 255) << 17) | (unsigned)s;
    }
}

// ---------------- K4: per-(bucket,slice) gather + LDS f32 accumulate + global merge ----------------
__global__ void __launch_bounds__(256) bucket_kernel(
        const unsigned int* __restrict__ bins, const int* __restrict__ gcur,
        const unsigned int* __restrict__ h, float* __restrict__ agg1) {
    __shared__ float agg[BNODE * 33];   // 33.8 KB -> 4 blocks/CU
    for (int i = threadIdx.x; i < BNODE * 33; i += 256) agg[i] = 0.f;
    __syncthreads();

    const int b  = blockIdx.x >> 1;
    const int sl = blockIdx.x & 1;
    const int m  = min(gcur[b], CAP);
    const int e0 = (sl == 0) ? 0 : m / 2;
    const int e1 = (sl == 0) ? m / 2 : m;
    const unsigned int* bb = bins + (size_t)b * CAP;
    const int lane8 = threadIdx.x & 7;
    const int g = threadIdx.x >> 3;     // 32 edge groups

    // 8 lanes per edge: coalesced 64B h-row gather -> LDS f32 atomic accumulate
    for (int j = e0 + g; j < e1; j += 32) {
        unsigned p = bb[j];
        int s = p & 0x1FFFF;
        int local = p >> 17;
        uint2 hv = *(const uint2*)(h + (size_t)s * 16 + lane8 * 2);
        float2 lo = __half22float2(*(__half2*)&hv.x);
        float2 hi = __half22float2(*(__half2*)&hv.y);
        float* ap = agg + local * 33 + lane8 * 4;
        atomicAdd(ap + 0, lo.x);
        atomicAdd(ap + 1, lo.y);
        atomicAdd(ap + 2, hi.x);
        atomicAdd(ap + 3, hi.y);
    }
    __syncthreads();

    // merge partial tile into global f32 agg1 (per-node, coalesced atomics)
    const int n0 = b * BNODE;
    for (int idx = threadIdx.x; idx < BNODE * HF; idx += 256) {
        int local = idx >> 5;
        int c = idx & 31;
        int n = n0 + local;
        if (n < NN) atomicAdd(&agg1[(size_t)n * HF + c], agg[local * 33 + c]);
    }
}

// ---------------- K5: wgt[src] += rsqrt(deg_in[dst]) ----------------
__global__ void wgt_kernel(const int* __restrict__ src, const int* __restrict__ dst,
                           const int* __restrict__ deg_in, float* __restrict__ wgt) {
    int e = blockIdx.x * blockDim.x + threadIdx.x;
    if (e < NE) {
        float riv = rsqrtf(fmaxf((float)deg_in[dst[e]], 1.0f));
        atomicAdd(&wgt[src[e]], riv);
    }
}

// ---------------- K6: v[32] = sum_n (rs_out*wgt) * relu(agg1*rs_in + b1) ----------------
__global__ void __launch_bounds__(256) reduce_kernel(
        const float* __restrict__ agg1,
        const int* __restrict__ deg_in, const int* __restrict__ deg_out,
        const float* __restrict__ wgt, const float* __restrict__ b1,
        float* __restrict__ v) {
    const int lane8 = threadIdx.x & 7;
    const int f0 = lane8 * 4;
    const int group = (blockIdx.x * blockDim.x + threadIdx.x) >> 3;
    const int ngroups = (gridDim.x * blockDim.x) >> 3;

    float b1r[4];
    #pragma unroll
    for (int c = 0; c < 4; ++c) b1r[c] = b1[f0 + c];

    float vacc[4] = {0.f, 0.f, 0.f, 0.f};
    for (int n = group; n < NN; n += ngroups) {
        float4 a = *(const float4*)(agg1 + (size_t)n * HF + f0);
        float rs_in  = rsqrtf(fmaxf((float)deg_in[n], 1.0f));
        float rs_out = rsqrtf(fmaxf((float)deg_out[n], 1.0f));
        float alpha = rs_out * wgt[n];
        vacc[0] += alpha * fmaxf(fmaf(a.x, rs_in, b1r[0]), 0.f);
        vacc[1] += alpha * fmaxf(fmaf(a.y, rs_in, b1r[1]), 0.f);
        vacc[2] += alpha * fmaxf(fmaf(a.z, rs_in, b1r[2]), 0.f);
        vacc[3] += alpha * fmaxf(fmaf(a.w, rs_in, b1r[3]), 0.f);
    }
    #pragma unroll
    for (int c = 0; c < 4; ++c) {
        vacc[c] += __shfl_xor(vacc[c], 8, 64);
        vacc[c] += __shfl_xor(vacc[c], 16, 64);
        vacc[c] += __shfl_xor(vacc[c], 32, 64);
    }
    __shared__ float vl[32];
    if (threadIdx.x < 32) vl[threadIdx.x] = 0.f;
    __syncthreads();
    if ((threadIdx.x & 63) < 8) {
        #pragma unroll
        for (int c = 0; c < 4; ++c) atomicAdd(&vl[f0 + c], vacc[c]);
    }
    __syncthreads();
    if (threadIdx.x < 32) atomicAdd(&v[threadIdx.x], vl[threadIdx.x]);
}

// ---------------- K7: out = (v @ W2)/N + b2 ----------------
__global__ void final_kernel(const float* __restrict__ v, const float* __restrict__ W2,
                             const float* __restrict__ b2, float* __restrict__ out) {
    int c = threadIdx.x;
    if (c < CF) {
        float s = 0.f;
        #pragma unroll
        for (int k = 0; k < HF; ++k) s = fmaf(v[k], W2[k * CF + c], s);
        out[c] = s * (1.0f / NN) + b2[c];
    }
}

static inline size_t align256(size_t x) { return (x + 255) & ~(size_t)255; }

extern "C" void kernel_launch(void* const* d_in, const int* in_sizes, int n_in,
                              void* d_out, int out_size, void* d_ws, size_t ws_size,
                              hipStream_t stream) {
    const float* x   = (const float*)d_in[0];
    const int*   src = (const int*)  d_in[1];
    const int*   dst = (const int*)  d_in[2];
    const float* W1  = (const float*)d_in[3];
    const float* b1  = (const float*)d_in[4];
    const float* W2  = (const float*)d_in[5];
    const float* b2  = (const float*)d_in[6];
    float* out = (float*)d_out;

    char* base = (char*)d_ws;
    size_t off = 0;
    int*   deg_out = (int*)(base + off);   off = align256(off + NN * 4);
    int*   deg_in  = (int*)(base + off);   off = align256(off + NN * 4);
    float* wgt     = (float*)(base + off); off = align256(off + NN * 4);
    int*   gcur    = (int*)(base + off);   off = align256(off + NBKT * 4);
    float* v       = (float*)(base + off); off = align256(off + 32 * 4);
    float* agg1    = (float*)(base + off); off = align256(off + (size_t)NN * HF * 4);
    size_t zero_bytes = off;               // everything above must start at 0
    unsigned int* h    = (unsigned int*)(base + off); off = align256(off + (size_t)NN * 16 * 4);
    unsigned int* bins = (unsigned int*)(base + off); off = align256(off + (size_t)NBKT * CAP * 4);

    hipMemsetAsync(base, 0, zero_bytes, stream);

    const int B = 256;
    deg_kernel<<<(NE + B - 1) / B, B, 0, stream>>>(src, dst, deg_out, deg_in);
    xw1_kernel<<<(NN + B - 1) / B, B, 0, stream>>>(x, W1, deg_out, h);
    bin_kernel<<<NBLK_BIN, B, 0, stream>>>(src, dst, gcur, bins);
    bucket_kernel<<<NBKT * SPLIT, B, 0, stream>>>(bins, gcur, h, agg1);
    wgt_kernel<<<(NE + B - 1) / B, B, 0, stream>>>(src, dst, deg_in, wgt);
    reduce_kernel<<<1024, B, 0, stream>>>(agg1, deg_in, deg_out, wgt, b1, v);
    final_kernel<<<1, 64, 0, stream>>>(v, W2, b2, out);
}

// Round 6
// 316.672 us; speedup vs baseline: 1.9632x; 1.9632x over previous
//
#include <hip/hip_runtime.h>
#include <hip/hip_fp16.h>

#define NN 100000      // nodes
#define NE 1600000     // edges
#define INF 32
#define HF 32
#define CF 8

#define BNODE 64                         // nodes per bucket
#define NBKT 1563                        // ceil(NN/BNODE)
#define CAP 1280                         // slots/bucket: mean 1024, sigma 32 -> +8 sigma
#define CHUNK 2048                       // edges per bin block
#define NBLK_BIN ((NE + CHUNK - 1) / CHUNK)  // 782

// ---------------- K1: degree histograms ----------------
__global__ void deg_kernel(const int* __restrict__ src, const int* __restrict__ dst,
                           int* __restrict__ deg_out, int* __restrict__ deg_in) {
    int e = blockIdx.x * blockDim.x + threadIdx.x;
    if (e < NE) {
        atomicAdd(&deg_out[src[e]], 1);
        atomicAdd(&deg_in[dst[e]], 1);
    }
}

// ---------------- K2: h = (x @ W1) * rsqrt(deg_out), packed f16 pairs ----------------
__global__ void xw1_kernel(const float* __restrict__ x, const float* __restrict__ W1,
                           const int* __restrict__ deg_out, unsigned int* __restrict__ h) {
    __shared__ float w[INF * HF];
    for (int i = threadIdx.x; i < INF * HF; i += blockDim.x) w[i] = W1[i];
    __syncthreads();
    int n = blockIdx.x * blockDim.x + threadIdx.x;
    if (n >= NN) return;

    float xr[INF];
    const float4* xp = (const float4*)(x + (size_t)n * INF);
    #pragma unroll
    for (int i = 0; i < INF / 4; ++i) {
        float4 v = xp[i];
        xr[4*i+0] = v.x; xr[4*i+1] = v.y; xr[4*i+2] = v.z; xr[4*i+3] = v.w;
    }
    float acc[HF];
    #pragma unroll
    for (int c = 0; c < HF; ++c) acc[c] = 0.0f;
    #pragma unroll
    for (int k = 0; k < INF; ++k) {
        float xv = xr[k];
        #pragma unroll
        for (int c = 0; c < HF; ++c) acc[c] = fmaf(xv, w[k * HF + c], acc[c]);
    }
    float rs = rsqrtf(fmaxf((float)deg_out[n], 1.0f));
    unsigned int pk[HF / 2];
    #pragma unroll
    for (int i = 0; i < HF / 2; ++i) {
        __half2 p = __floats2half2_rn(acc[2*i] * rs, acc[2*i+1] * rs);
        pk[i] = *(unsigned int*)&p;
    }
    uint4* hp = (uint4*)(h + (size_t)n * (HF / 2));
    #pragma unroll
    for (int i = 0; i < 4; ++i) {
        uint4 v;
        v.x = pk[4*i+0]; v.y = pk[4*i+1]; v.z = pk[4*i+2]; v.w = pk[4*i+3];
        hp[i] = v;
    }
}

// ---------------- K3: bin edges into 64-node dst buckets ----------------
// payload = (dst & 63) << 17 | src   (src < 2^17)
__global__ void __launch_bounds__(256) bin_kernel(
        const int* __restrict__ src, const int* __restrict__ dst,
        int* __restrict__ gcur, unsigned int* __restrict__ bins) {
    __shared__ int cnt[NBKT];
    __shared__ int base[NBKT];
    for (int i = threadIdx.x; i < NBKT; i += 256) cnt[i] = 0;
    __syncthreads();
    int e0 = blockIdx.x * CHUNK;
    int e1 = min(e0 + CHUNK, NE);
    for (int e = e0 + threadIdx.x; e < e1; e += 256)
        atomicAdd(&cnt[dst[e] >> 6], 1);
    __syncthreads();
    for (int i = threadIdx.x; i < NBKT; i += 256) {
        int c = cnt[i];
        base[i] = c ? atomicAdd(&gcur[i], c) : 0;   // skip-zero: fewer global atomics
        cnt[i] = 0;
    }
    __syncthreads();
    for (int e = e0 + threadIdx.x; e < e1; e += 256) {
        int d = dst[e], s = src[e];
        int b = d >> 6;
        int off = base[b] + atomicAdd(&cnt[b], 1);
        if (off < CAP)
            bins[(size_t)b * CAP + off] = ((unsigned)(d & 63) << 17) | (unsigned)s;
    }
}

// ---------------- K4: wgt[src] += rsqrt(deg_in[dst]) ----------------
__global__ void wgt_kernel(const int* __restrict__ src, const int* __restrict__ dst,
                           const int* __restrict__ deg_in, float* __restrict__ wgt) {
    int e = blockIdx.x * blockDim.x + threadIdx.x;
    if (e < NE) {
        float riv = rsqrtf(fmaxf((float)deg_in[dst[e]], 1.0f));
        atomicAdd(&wgt[src[e]], riv);
    }
}

// ---------------- K5: per-bucket counting sort + register-accumulate gather + fused tail ----------------
__global__ void __launch_bounds__(256) gather_kernel(
        const unsigned int* __restrict__ bins, const int* __restrict__ gcur,
        const unsigned int* __restrict__ h, const int* __restrict__ deg_out,
        const float* __restrict__ wgt, const float* __restrict__ b1,
        float* __restrict__ v) {
    __shared__ int s_cnt[BNODE];
    __shared__ int s_start[BNODE];
    __shared__ int s_cur[BNODE];
    __shared__ int s_src[CAP];
    __shared__ float vl[32];
    const int tid = threadIdx.x;
    const int b = blockIdx.x;
    const int m = min(gcur[b], CAP);
    const unsigned int* bb = bins + (size_t)b * CAP;

    if (tid < BNODE) s_cnt[tid] = 0;
    __syncthreads();
    // count per local dst
    for (int j = tid; j < m; j += 256) atomicAdd(&s_cnt[bb[j] >> 17], 1);
    __syncthreads();
    // exclusive scan of 64 counters on wave 0
    if (tid < 64) {
        int c = s_cnt[tid];
        int sc = c;
        #pragma unroll
        for (int off = 1; off < 64; off <<= 1) {
            int t = __shfl_up(sc, off, 64);
            if (tid >= off) sc += t;
        }
        s_start[tid] = sc - c;
        s_cur[tid] = sc - c;
    }
    __syncthreads();
    // scatter srcs into dst-sorted LDS order
    for (int j = tid; j < m; j += 256) {
        unsigned p = bb[j];
        int pos = atomicAdd(&s_cur[p >> 17], 1);
        s_src[pos] = (int)(p & 0x1FFFF);
    }
    __syncthreads();

    const int lane8 = tid & 7;         // feature sub-group: 4 channels each
    const int g = tid >> 3;            // 32 node-groups
    float b1r[4];
    #pragma unroll
    for (int c = 0; c < 4; ++c) b1r[c] = b1[lane8 * 4 + c];
    float vacc[4] = {0.f, 0.f, 0.f, 0.f};

    #define ACCQ(q) { float2 lo_ = __half22float2(*(__half2*)&(q).x); \
                      float2 hi_ = __half22float2(*(__half2*)&(q).y); \
                      a0 += lo_.x; a1 += lo_.y; a2 += hi_.x; a3 += hi_.y; }

    for (int local = g; local < BNODE; local += 32) {
        int n = b * BNODE + local;
        if (n >= NN) continue;
        int beg = s_start[local];
        int cn = s_cnt[local];
        int end = beg + cn;
        float a0 = 0.f, a1 = 0.f, a2 = 0.f, a3 = 0.f;
        int j = beg;
        for (; j + 8 <= end; j += 8) {          // 8 independent gathers in flight
            int t0 = s_src[j+0], t1 = s_src[j+1], t2 = s_src[j+2], t3 = s_src[j+3];
            int t4 = s_src[j+4], t5 = s_src[j+5], t6 = s_src[j+6], t7 = s_src[j+7];
            uint2 q0 = *(const uint2*)(h + (size_t)t0 * 16 + lane8 * 2);
            uint2 q1 = *(const uint2*)(h + (size_t)t1 * 16 + lane8 * 2);
            uint2 q2 = *(const uint2*)(h + (size_t)t2 * 16 + lane8 * 2);
            uint2 q3 = *(const uint2*)(h + (size_t)t3 * 16 + lane8 * 2);
            uint2 q4 = *(const uint2*)(h + (size_t)t4 * 16 + lane8 * 2);
            uint2 q5 = *(const uint2*)(h + (size_t)t5 * 16 + lane8 * 2);
            uint2 q6 = *(const uint2*)(h + (size_t)t6 * 16 + lane8 * 2);
            uint2 q7 = *(const uint2*)(h + (size_t)t7 * 16 + lane8 * 2);
            ACCQ(q0) ACCQ(q1) ACCQ(q2) ACCQ(q3)
            ACCQ(q4) ACCQ(q5) ACCQ(q6) ACCQ(q7)
        }
        for (; j + 4 <= end; j += 4) {
            int t0 = s_src[j+0], t1 = s_src[j+1], t2 = s_src[j+2], t3 = s_src[j+3];
            uint2 q0 = *(const uint2*)(h + (size_t)t0 * 16 + lane8 * 2);
            uint2 q1 = *(const uint2*)(h + (size_t)t1 * 16 + lane8 * 2);
            uint2 q2 = *(const uint2*)(h + (size_t)t2 * 16 + lane8 * 2);
            uint2 q3 = *(const uint2*)(h + (size_t)t3 * 16 + lane8 * 2);
            ACCQ(q0) ACCQ(q1) ACCQ(q2) ACCQ(q3)
        }
        for (; j < end; ++j) {
            int t0 = s_src[j];
            uint2 q0 = *(const uint2*)(h + (size_t)t0 * 16 + lane8 * 2);
            ACCQ(q0)
        }
        float rs_in  = rsqrtf(fmaxf((float)cn, 1.0f));
        float rs_out = rsqrtf(fmaxf((float)deg_out[n], 1.0f));
        float alpha = rs_out * wgt[n];
        vacc[0] += alpha * fmaxf(fmaf(a0, rs_in, b1r[0]), 0.f);
        vacc[1] += alpha * fmaxf(fmaf(a1, rs_in, b1r[1]), 0.f);
        vacc[2] += alpha * fmaxf(fmaf(a2, rs_in, b1r[2]), 0.f);
        vacc[3] += alpha * fmaxf(fmaf(a3, rs_in, b1r[3]), 0.f);
    }
    #undef ACCQ

    // cross-group reduce within wave (lanes differing in bits 3,4,5)
    #pragma unroll
    for (int c = 0; c < 4; ++c) {
        vacc[c] += __shfl_xor(vacc[c], 8, 64);
        vacc[c] += __shfl_xor(vacc[c], 16, 64);
        vacc[c] += __shfl_xor(vacc[c], 32, 64);
    }
    if (tid < 32) vl[tid] = 0.f;
    __syncthreads();
    if ((tid & 63) < 8) {
        #pragma unroll
        for (int c = 0; c < 4; ++c) atomicAdd(&vl[lane8 * 4 + c], vacc[c]);
    }
    __syncthreads();
    if (tid < 32) atomicAdd(&v[tid], vl[tid]);
}

// ---------------- K6: out = (v @ W2)/N + b2 ----------------
__global__ void final_kernel(const float* __restrict__ v, const float* __restrict__ W2,
                             const float* __restrict__ b2, float* __restrict__ out) {
    int c = threadIdx.x;
    if (c < CF) {
        float s = 0.f;
        #pragma unroll
        for (int k = 0; k < HF; ++k) s = fmaf(v[k], W2[k * CF + c], s);
        out[c] = s * (1.0f / NN) + b2[c];
    }
}

static inline size_t align256(size_t x) { return (x + 255) & ~(size_t)255; }

extern "C" void kernel_launch(void* const* d_in, const int* in_sizes, int n_in,
                              void* d_out, int out_size, void* d_ws, size_t ws_size,
                              hipStream_t stream) {
    const float* x   = (const float*)d_in[0];
    const int*   src = (const int*)  d_in[1];
    const int*   dst = (const int*)  d_in[2];
    const float* W1  = (const float*)d_in[3];
    const float* b1  = (const float*)d_in[4];
    const float* W2  = (const float*)d_in[5];
    const float* b2  = (const float*)d_in[6];
    float* out = (float*)d_out;

    char* base = (char*)d_ws;
    size_t off = 0;
    int*   deg_out = (int*)(base + off);   off = align256(off + NN * 4);
    int*   deg_in  = (int*)(base + off);   off = align256(off + NN * 4);
    float* wgt     = (float*)(base + off); off = align256(off + NN * 4);
    int*   gcur    = (int*)(base + off);   off = align256(off + NBKT * 4);
    float* v       = (float*)(base + off); off = align256(off + 32 * 4);
    size_t zero_bytes = off;               // everything above must start at 0
    unsigned int* h    = (unsigned int*)(base + off); off = align256(off + (size_t)NN * 16 * 4);
    unsigned int* bins = (unsigned int*)(base + off); off = align256(off + (size_t)NBKT * CAP * 4);

    hipMemsetAsync(base, 0, zero_bytes, stream);

    const int B = 256;
    deg_kernel<<<(NE + B - 1) / B, B, 0, stream>>>(src, dst, deg_out, deg_in);
    xw1_kernel<<<(NN + B - 1) / B, B, 0, stream>>>(x, W1, deg_out, h);
    bin_kernel<<<NBLK_BIN, B, 0, stream>>>(src, dst, gcur, bins);
    wgt_kernel<<<(NE + B - 1) / B, B, 0, stream>>>(src, dst, deg_in, wgt);
    gather_kernel<<<NBKT, B, 0, stream>>>(bins, gcur, h, deg_out, wgt, b1, v);
    final_kernel<<<1, 64, 0, stream>>>(v, W2, b2, out);
}

// Round 7
// 147.553 us; speedup vs baseline: 4.2134x; 2.1462x over previous
//
#include <hip/hip_runtime.h>
#include <hip/hip_fp16.h>

#define NN 100000      // nodes
#define NE 1600000     // edges
#define INF 32
#define HF 32
#define CF 8

#define BNODE 64                         // nodes per bucket
#define NBKT 1563                        // ceil(NN/BNODE)
#define CAP 1280                         // slots/bucket: mean 1024, sigma 32 -> +8 sigma
#define CHUNK 2048                       // edges per bin block
#define NBLK_BIN ((NE + CHUNK - 1) / CHUNK)  // 782

// ---------------- K1: dual binning (by dst bucket AND by src bucket) ----------------
// bins_d payload: (dst & 63) << 17 | src ; bins_s payload: (src & 63) << 17 | dst
__global__ void __launch_bounds__(256) bin2_kernel(
        const int* __restrict__ src, const int* __restrict__ dst,
        int* __restrict__ gcur_d, int* __restrict__ gcur_s,
        unsigned int* __restrict__ bins_d, unsigned int* __restrict__ bins_s) {
    __shared__ int cnt_d[NBKT];
    __shared__ int base_d[NBKT];
    __shared__ int cnt_s[NBKT];
    __shared__ int base_s[NBKT];
    for (int i = threadIdx.x; i < NBKT; i += 256) { cnt_d[i] = 0; cnt_s[i] = 0; }
    __syncthreads();
    int e0 = blockIdx.x * CHUNK;
    int e1 = min(e0 + CHUNK, NE);
    for (int e = e0 + threadIdx.x; e < e1; e += 256) {
        atomicAdd(&cnt_d[dst[e] >> 6], 1);
        atomicAdd(&cnt_s[src[e] >> 6], 1);
    }
    __syncthreads();
    for (int i = threadIdx.x; i < NBKT; i += 256) {
        int c = cnt_d[i];
        base_d[i] = c ? atomicAdd(&gcur_d[i], c) : 0;
        cnt_d[i] = 0;
        c = cnt_s[i];
        base_s[i] = c ? atomicAdd(&gcur_s[i], c) : 0;
        cnt_s[i] = 0;
    }
    __syncthreads();
    for (int e = e0 + threadIdx.x; e < e1; e += 256) {
        int d = dst[e], s = src[e];
        int b = d >> 6;
        int off = base_d[b] + atomicAdd(&cnt_d[b], 1);
        if (off < CAP)
            bins_d[(size_t)b * CAP + off] = ((unsigned)(d & 63) << 17) | (unsigned)s;
        b = s >> 6;
        off = base_s[b] + atomicAdd(&cnt_s[b], 1);
        if (off < CAP)
            bins_s[(size_t)b * CAP + off] = ((unsigned)(s & 63) << 17) | (unsigned)d;
    }
}

// ---------------- K2: deg_in from dst-bins (coalesced write, no global atomics) ----------------
__global__ void __launch_bounds__(256) count_kernel(
        const unsigned int* __restrict__ bins_d, const int* __restrict__ gcur_d,
        int* __restrict__ deg_in) {
    __shared__ int cnt[BNODE];
    const int tid = threadIdx.x;
    const int b = blockIdx.x;
    if (tid < BNODE) cnt[tid] = 0;
    __syncthreads();
    const int m = min(gcur_d[b], CAP);
    const unsigned int* bb = bins_d + (size_t)b * CAP;
    for (int j = tid; j < m; j += 256) atomicAdd(&cnt[bb[j] >> 17], 1);
    __syncthreads();
    if (tid < BNODE) {
        int n = b * BNODE + tid;
        if (n < NN) deg_in[n] = cnt[tid];
    }
}

// ---------------- K3: deg_out + wgt from src-bins (LDS atomics, coalesced writes) ----------------
// wgt[n] = sum_{e: src=n} rsqrt(max(deg_in[dst[e]],1))
__global__ void __launch_bounds__(256) srcside_kernel(
        const unsigned int* __restrict__ bins_s, const int* __restrict__ gcur_s,
        const int* __restrict__ deg_in,
        int* __restrict__ deg_out, float* __restrict__ wgt) {
    __shared__ int cnt[BNODE];
    __shared__ float sw[BNODE];
    const int tid = threadIdx.x;
    const int b = blockIdx.x;
    if (tid < BNODE) { cnt[tid] = 0; sw[tid] = 0.f; }
    __syncthreads();
    const int m = min(gcur_s[b], CAP);
    const unsigned int* bb = bins_s + (size_t)b * CAP;
    for (int j = tid; j < m; j += 256) {
        unsigned p = bb[j];
        int local = p >> 17;
        int d = p & 0x1FFFF;
        float riv = rsqrtf(fmaxf((float)deg_in[d], 1.0f));   // deg_in: 400 KB, L2-resident
        atomicAdd(&cnt[local], 1);
        atomicAdd(&sw[local], riv);
    }
    __syncthreads();
    if (tid < BNODE) {
        int n = b * BNODE + tid;
        if (n < NN) { deg_out[n] = cnt[tid]; wgt[n] = sw[tid]; }
    }
}

// ---------------- K4: h = (x @ W1) * rsqrt(deg_out), packed f16 pairs ----------------
__global__ void xw1_kernel(const float* __restrict__ x, const float* __restrict__ W1,
                           const int* __restrict__ deg_out, unsigned int* __restrict__ h) {
    __shared__ float w[INF * HF];
    for (int i = threadIdx.x; i < INF * HF; i += blockDim.x) w[i] = W1[i];
    __syncthreads();
    int n = blockIdx.x * blockDim.x + threadIdx.x;
    if (n >= NN) return;

    float xr[INF];
    const float4* xp = (const float4*)(x + (size_t)n * INF);
    #pragma unroll
    for (int i = 0; i < INF / 4; ++i) {
        float4 v = xp[i];
        xr[4*i+0] = v.x; xr[4*i+1] = v.y; xr[4*i+2] = v.z; xr[4*i+3] = v.w;
    }
    float acc[HF];
    #pragma unroll
    for (int c = 0; c < HF; ++c) acc[c] = 0.0f;
    #pragma unroll
    for (int k = 0; k < INF; ++k) {
        float xv = xr[k];
        #pragma unroll
        for (int c = 0; c < HF; ++c) acc[c] = fmaf(xv, w[k * HF + c], acc[c]);
    }
    float rs = rsqrtf(fmaxf((float)deg_out[n], 1.0f));
    unsigned int pk[HF / 2];
    #pragma unroll
    for (int i = 0; i < HF / 2; ++i) {
        __half2 p = __floats2half2_rn(acc[2*i] * rs, acc[2*i+1] * rs);
        pk[i] = *(unsigned int*)&p;
    }
    uint4* hp = (uint4*)(h + (size_t)n * (HF / 2));
    #pragma unroll
    for (int i = 0; i < 4; ++i) {
        uint4 v;
        v.x = pk[4*i+0]; v.y = pk[4*i+1]; v.z = pk[4*i+2]; v.w = pk[4*i+3];
        hp[i] = v;
    }
}

// ---------------- K5: per-bucket counting sort + register-accumulate gather + fused tail ----------------
__global__ void __launch_bounds__(256) gather_kernel(
        const unsigned int* __restrict__ bins, const int* __restrict__ gcur,
        const unsigned int* __restrict__ h, const int* __restrict__ deg_out,
        const float* __restrict__ wgt, const float* __restrict__ b1,
        float* __restrict__ v) {
    __shared__ int s_cnt[BNODE];
    __shared__ int s_start[BNODE];
    __shared__ int s_cur[BNODE];
    __shared__ int s_src[CAP];
    __shared__ float vl[32];
    const int tid = threadIdx.x;
    const int b = blockIdx.x;
    const int m = min(gcur[b], CAP);
    const unsigned int* bb = bins + (size_t)b * CAP;

    if (tid < BNODE) s_cnt[tid] = 0;
    __syncthreads();
    for (int j = tid; j < m; j += 256) atomicAdd(&s_cnt[bb[j] >> 17], 1);
    __syncthreads();
    if (tid < 64) {
        int c = s_cnt[tid];
        int sc = c;
        #pragma unroll
        for (int off = 1; off < 64; off <<= 1) {
            int t = __shfl_up(sc, off, 64);
            if (tid >= off) sc += t;
        }
        s_start[tid] = sc - c;
        s_cur[tid] = sc - c;
    }
    __syncthreads();
    for (int j = tid; j < m; j += 256) {
        unsigned p = bb[j];
        int pos = atomicAdd(&s_cur[p >> 17], 1);
        s_src[pos] = (int)(p & 0x1FFFF);
    }
    __syncthreads();

    const int lane8 = tid & 7;
    const int g = tid >> 3;
    float b1r[4];
    #pragma unroll
    for (int c = 0; c < 4; ++c) b1r[c] = b1[lane8 * 4 + c];
    float vacc[4] = {0.f, 0.f, 0.f, 0.f};

    #define ACCQ(q) { float2 lo_ = __half22float2(*(__half2*)&(q).x); \
                      float2 hi_ = __half22float2(*(__half2*)&(q).y); \
                      a0 += lo_.x; a1 += lo_.y; a2 += hi_.x; a3 += hi_.y; }

    for (int local = g; local < BNODE; local += 32) {
        int n = b * BNODE + local;
        if (n >= NN) continue;
        int beg = s_start[local];
        int cn = s_cnt[local];
        int end = beg + cn;
        float a0 = 0.f, a1 = 0.f, a2 = 0.f, a3 = 0.f;
        int j = beg;
        for (; j + 8 <= end; j += 8) {
            int t0 = s_src[j+0], t1 = s_src[j+1], t2 = s_src[j+2], t3 = s_src[j+3];
            int t4 = s_src[j+4], t5 = s_src[j+5], t6 = s_src[j+6], t7 = s_src[j+7];
            uint2 q0 = *(const uint2*)(h + (size_t)t0 * 16 + lane8 * 2);
            uint2 q1 = *(const uint2*)(h + (size_t)t1 * 16 + lane8 * 2);
            uint2 q2 = *(const uint2*)(h + (size_t)t2 * 16 + lane8 * 2);
            uint2 q3 = *(const uint2*)(h + (size_t)t3 * 16 + lane8 * 2);
            uint2 q4 = *(const uint2*)(h + (size_t)t4 * 16 + lane8 * 2);
            uint2 q5 = *(const uint2*)(h + (size_t)t5 * 16 + lane8 * 2);
            uint2 q6 = *(const uint2*)(h + (size_t)t6 * 16 + lane8 * 2);
            uint2 q7 = *(const uint2*)(h + (size_t)t7 * 16 + lane8 * 2);
            ACCQ(q0) ACCQ(q1) ACCQ(q2) ACCQ(q3)
            ACCQ(q4) ACCQ(q5) ACCQ(q6) ACCQ(q7)
        }
        for (; j + 4 <= end; j += 4) {
            int t0 = s_src[j+0], t1 = s_src[j+1], t2 = s_src[j+2], t3 = s_src[j+3];
            uint2 q0 = *(const uint2*)(h + (size_t)t0 * 16 + lane8 * 2);
            uint2 q1 = *(const uint2*)(h + (size_t)t1 * 16 + lane8 * 2);
            uint2 q2 = *(const uint2*)(h + (size_t)t2 * 16 + lane8 * 2);
            uint2 q3 = *(const uint2*)(h + (size_t)t3 * 16 + lane8 * 2);
            ACCQ(q0) ACCQ(q1) ACCQ(q2) ACCQ(q3)
        }
        for (; j < end; ++j) {
            int t0 = s_src[j];
            uint2 q0 = *(const uint2*)(h + (size_t)t0 * 16 + lane8 * 2);
            ACCQ(q0)
        }
        float rs_in  = rsqrtf(fmaxf((float)cn, 1.0f));
        float rs_out = rsqrtf(fmaxf((float)deg_out[n], 1.0f));
        float alpha = rs_out * wgt[n];
        vacc[0] += alpha * fmaxf(fmaf(a0, rs_in, b1r[0]), 0.f);
        vacc[1] += alpha * fmaxf(fmaf(a1, rs_in, b1r[1]), 0.f);
        vacc[2] += alpha * fmaxf(fmaf(a2, rs_in, b1r[2]), 0.f);
        vacc[3] += alpha * fmaxf(fmaf(a3, rs_in, b1r[3]), 0.f);
    }
    #undef ACCQ

    #pragma unroll
    for (int c = 0; c < 4; ++c) {
        vacc[c] += __shfl_xor(vacc[c], 8, 64);
        vacc[c] += __shfl_xor(vacc[c], 16, 64);
        vacc[c] += __shfl_xor(vacc[c], 32, 64);
    }
    if (tid < 32) vl[tid] = 0.f;
    __syncthreads();
    if ((tid & 63) < 8) {
        #pragma unroll
        for (int c = 0; c < 4; ++c) atomicAdd(&vl[lane8 * 4 + c], vacc[c]);
    }
    __syncthreads();
    if (tid < 32) atomicAdd(&v[tid], vl[tid]);
}

// ---------------- K6: out = (v @ W2)/N + b2 ----------------
__global__ void final_kernel(const float* __restrict__ v, const float* __restrict__ W2,
                             const float* __restrict__ b2, float* __restrict__ out) {
    int c = threadIdx.x;
    if (c < CF) {
        float s = 0.f;
        #pragma unroll
        for (int k = 0; k < HF; ++k) s = fmaf(v[k], W2[k * CF + c], s);
        out[c] = s * (1.0f / NN) + b2[c];
    }
}

static inline size_t align256(size_t x) { return (x + 255) & ~(size_t)255; }

extern "C" void kernel_launch(void* const* d_in, const int* in_sizes, int n_in,
                              void* d_out, int out_size, void* d_ws, size_t ws_size,
                              hipStream_t stream) {
    const float* x   = (const float*)d_in[0];
    const int*   src = (const int*)  d_in[1];
    const int*   dst = (const int*)  d_in[2];
    const float* W1  = (const float*)d_in[3];
    const float* b1  = (const float*)d_in[4];
    const float* W2  = (const float*)d_in[5];
    const float* b2  = (const float*)d_in[6];
    float* out = (float*)d_out;

    char* base = (char*)d_ws;
    size_t off = 0;
    int*   gcur_d = (int*)(base + off);   off = align256(off + NBKT * 4);
    int*   gcur_s = (int*)(base + off);   off = align256(off + NBKT * 4);
    float* v      = (float*)(base + off); off = align256(off + 32 * 4);
    size_t zero_bytes = off;              // only cursors + v need zeroing
    int*   deg_in  = (int*)(base + off);  off = align256(off + NN * 4);
    int*   deg_out = (int*)(base + off);  off = align256(off + NN * 4);
    float* wgt     = (float*)(base + off);off = align256(off + NN * 4);
    unsigned int* h      = (unsigned int*)(base + off); off = align256(off + (size_t)NN * 16 * 4);
    unsigned int* bins_d = (unsigned int*)(base + off); off = align256(off + (size_t)NBKT * CAP * 4);
    unsigned int* bins_s = (unsigned int*)(base + off); off = align256(off + (size_t)NBKT * CAP * 4);

    hipMemsetAsync(base, 0, zero_bytes, stream);

    const int B = 256;
    bin2_kernel<<<NBLK_BIN, B, 0, stream>>>(src, dst, gcur_d, gcur_s, bins_d, bins_s);
    count_kernel<<<NBKT, B, 0, stream>>>(bins_d, gcur_d, deg_in);
    srcside_kernel<<<NBKT, B, 0, stream>>>(bins_s, gcur_s, deg_in, deg_out, wgt);
    xw1_kernel<<<(NN + B - 1) / B, B, 0, stream>>>(x, W1, deg_out, h);
    gather_kernel<<<NBKT, B, 0, stream>>>(bins_d, gcur_d, h, deg_out, wgt, b1, v);
    final_kernel<<<1, 64, 0, stream>>>(v, W2, b2, out);
}

// Round 8
// 128.883 us; speedup vs baseline: 4.8238x; 1.1449x over previous
//
#include <hip/hip_runtime.h>
#include <hip/hip_fp16.h>

#define NN 100000      // nodes
#define NE 1600000     // edges
#define INF 32
#define HF 32
#define CF 8

// coarse: 2048-node buckets
#define SH1 11
#define BN1 2048
#define NB1 49                           // ceil(100000/2048)
#define CAP1 36864                       // mean 32653, sigma ~180 -> +23 sigma
// fine: 64-node buckets (32 per coarse bucket)
#define BNODE 64
#define NBF (NB1 * 32)                   // 1568
#define CAPF 1280                        // mean 1024, sigma 32 -> +8 sigma
#define CHUNK 2048
#define NBLK_BIN ((NE + CHUNK - 1) / CHUNK)  // 782

// ---------------- K1: dual COARSE binning (dst side + src side) ----------------
// d payload: (dst & 2047) << 17 | src ; s payload: (src & 2047) << 17 | dst
__global__ void __launch_bounds__(256) bin_coarse_kernel(
        const int* __restrict__ src, const int* __restrict__ dst,
        int* __restrict__ gcur_d, int* __restrict__ gcur_s,
        unsigned int* __restrict__ bins_d, unsigned int* __restrict__ bins_s) {
    __shared__ int cnt_d[NB1], base_d[NB1], cnt_s[NB1], base_s[NB1];
    if (threadIdx.x < NB1) { cnt_d[threadIdx.x] = 0; cnt_s[threadIdx.x] = 0; }
    __syncthreads();
    int e0 = blockIdx.x * CHUNK;
    int e1 = min(e0 + CHUNK, NE);
    for (int e = e0 + threadIdx.x; e < e1; e += 256) {
        atomicAdd(&cnt_d[dst[e] >> SH1], 1);
        atomicAdd(&cnt_s[src[e] >> SH1], 1);
    }
    __syncthreads();
    if (threadIdx.x < NB1) {
        int c = cnt_d[threadIdx.x];
        base_d[threadIdx.x] = c ? atomicAdd(&gcur_d[threadIdx.x], c) : 0;
        cnt_d[threadIdx.x] = 0;
        c = cnt_s[threadIdx.x];
        base_s[threadIdx.x] = c ? atomicAdd(&gcur_s[threadIdx.x], c) : 0;
        cnt_s[threadIdx.x] = 0;
    }
    __syncthreads();
    for (int e = e0 + threadIdx.x; e < e1; e += 256) {
        int d = dst[e], s = src[e];
        int b = d >> SH1;
        int off = base_d[b] + atomicAdd(&cnt_d[b], 1);
        if (off < CAP1)
            bins_d[(size_t)b * CAP1 + off] = ((unsigned)(d & (BN1 - 1)) << 17) | (unsigned)s;
        b = s >> SH1;
        off = base_s[b] + atomicAdd(&cnt_s[b], 1);
        if (off < CAP1)
            bins_s[(size_t)b * CAP1 + off] = ((unsigned)(s & (BN1 - 1)) << 17) | (unsigned)d;
    }
}

// ---------------- K2: deg_in from coarse dst-bins (LDS count, dense atomic merge) ----------------
__global__ void __launch_bounds__(256) count_in_kernel(
        const unsigned int* __restrict__ bins_d, const int* __restrict__ gcur_d,
        int* __restrict__ deg_in) {
    __shared__ int cnt[BN1];
    const int cb = blockIdx.x >> 2;
    const int sl = blockIdx.x & 3;
    const int tid = threadIdx.x;
    for (int i = tid; i < BN1; i += 256) cnt[i] = 0;
    __syncthreads();
    const int m = min(gcur_d[cb], CAP1);
    const int beg = (sl * m) >> 2;
    const int end = ((sl + 1) * m) >> 2;
    const unsigned int* bb = bins_d + (size_t)cb * CAP1;
    for (int j = beg + tid; j < end; j += 256) atomicAdd(&cnt[bb[j] >> 17], 1);
    __syncthreads();
    for (int i = tid; i < BN1; i += 256) {
        int c = cnt[i];
        int n = cb * BN1 + i;
        if (c && n < NN) atomicAdd(&deg_in[n], c);
    }
}

// ---------------- K3: deg_out + wgt from coarse src-bins ----------------
// wgt[n] = sum_{e: src=n} rsqrt(max(deg_in[dst[e]],1))
__global__ void __launch_bounds__(256) srcside_kernel(
        const unsigned int* __restrict__ bins_s, const int* __restrict__ gcur_s,
        const int* __restrict__ deg_in,
        int* __restrict__ deg_out, float* __restrict__ wgt) {
    __shared__ int cnt[BN1];
    __shared__ float sw[BN1];
    const int cb = blockIdx.x >> 2;
    const int sl = blockIdx.x & 3;
    const int tid = threadIdx.x;
    for (int i = tid; i < BN1; i += 256) { cnt[i] = 0; sw[i] = 0.f; }
    __syncthreads();
    const int m = min(gcur_s[cb], CAP1);
    const int beg = (sl * m) >> 2;
    const int end = ((sl + 1) * m) >> 2;
    const unsigned int* bb = bins_s + (size_t)cb * CAP1;
    for (int j = beg + tid; j < end; j += 256) {
        unsigned p = bb[j];
        int local = p >> 17;
        int d = p & 0x1FFFF;
        float riv = rsqrtf(fmaxf((float)deg_in[d], 1.0f));
        atomicAdd(&cnt[local], 1);
        atomicAdd(&sw[local], riv);
    }
    __syncthreads();
    for (int i = tid; i < BN1; i += 256) {
        int c = cnt[i];
        int n = cb * BN1 + i;
        if (c && n < NN) {
            atomicAdd(&deg_out[n], c);
            atomicAdd(&wgt[n], sw[i]);
        }
    }
}

// ---------------- K4: fine binning of dst side (full-line writes) ----------------
__global__ void __launch_bounds__(256) bin_fine_kernel(
        const unsigned int* __restrict__ bins_d, const int* __restrict__ gcur_d,
        int* __restrict__ gcur_f, unsigned int* __restrict__ bins_f) {
    __shared__ int cnt[32], base[32];
    const int cb = blockIdx.x >> 4;
    const int sl = blockIdx.x & 15;
    const int tid = threadIdx.x;
    if (tid < 32) cnt[tid] = 0;
    __syncthreads();
    const int m = min(gcur_d[cb], CAP1);
    const int beg = (sl * m) >> 4;
    const int end = ((sl + 1) * m) >> 4;
    const unsigned int* bb = bins_d + (size_t)cb * CAP1;
    for (int j = beg + tid; j < end; j += 256)
        atomicAdd(&cnt[(bb[j] >> 17) >> 6], 1);
    __syncthreads();
    if (tid < 32) {
        int c = cnt[tid];
        base[tid] = c ? atomicAdd(&gcur_f[cb * 32 + tid], c) : 0;
        cnt[tid] = 0;
    }
    __syncthreads();
    for (int j = beg + tid; j < end; j += 256) {
        unsigned p = bb[j];
        int d10 = p >> 17;
        int f = d10 >> 6;
        int off = base[f] + atomicAdd(&cnt[f], 1);
        if (off < CAPF)
            bins_f[(size_t)(cb * 32 + f) * CAPF + off] =
                ((unsigned)(d10 & 63) << 17) | (p & 0x1FFFFu);
    }
}

// ---------------- K5: h = (x @ W1) * rsqrt(deg_out), packed f16 pairs ----------------
__global__ void xw1_kernel(const float* __restrict__ x, const float* __restrict__ W1,
                           const int* __restrict__ deg_out, unsigned int* __restrict__ h) {
    __shared__ float w[INF * HF];
    for (int i = threadIdx.x; i < INF * HF; i += blockDim.x) w[i] = W1[i];
    __syncthreads();
    int n = blockIdx.x * blockDim.x + threadIdx.x;
    if (n >= NN) return;

    float xr[INF];
    const float4* xp = (const float4*)(x + (size_t)n * INF);
    #pragma unroll
    for (int i = 0; i < INF / 4; ++i) {
        float4 v = xp[i];
        xr[4*i+0] = v.x; xr[4*i+1] = v.y; xr[4*i+2] = v.z; xr[4*i+3] = v.w;
    }
    float acc[HF];
    #pragma unroll
    for (int c = 0; c < HF; ++c) acc[c] = 0.0f;
    #pragma unroll
    for (int k = 0; k < INF; ++k) {
        float xv = xr[k];
        #pragma unroll
        for (int c = 0; c < HF; ++c) acc[c] = fmaf(xv, w[k * HF + c], acc[c]);
    }
    float rs = rsqrtf(fmaxf((float)deg_out[n], 1.0f));
    unsigned int pk[HF / 2];
    #pragma unroll
    for (int i = 0; i < HF / 2; ++i) {
        __half2 p = __floats2half2_rn(acc[2*i] * rs, acc[2*i+1] * rs);
        pk[i] = *(unsigned int*)&p;
    }
    uint4* hp = (uint4*)(h + (size_t)n * (HF / 2));
    #pragma unroll
    for (int i = 0; i < 4; ++i) {
        uint4 v;
        v.x = pk[4*i+0]; v.y = pk[4*i+1]; v.z = pk[4*i+2]; v.w = pk[4*i+3];
        hp[i] = v;
    }
}

// ---------------- K6: per-fine-bucket counting sort + register-accumulate gather + fused tail ----------------
__global__ void __launch_bounds__(256) gather_kernel(
        const unsigned int* __restrict__ bins, const int* __restrict__ gcur,
        const unsigned int* __restrict__ h, const int* __restrict__ deg_out,
        const float* __restrict__ wgt, const float* __restrict__ b1,
        float* __restrict__ v) {
    __shared__ int s_cnt[BNODE];
    __shared__ int s_start[BNODE];
    __shared__ int s_cur[BNODE];
    __shared__ int s_src[CAPF];
    __shared__ float vl[32];
    const int tid = threadIdx.x;
    const int b = blockIdx.x;
    const int m = min(gcur[b], CAPF);
    const unsigned int* bb = bins + (size_t)b * CAPF;

    if (tid < BNODE) s_cnt[tid] = 0;
    __syncthreads();
    for (int j = tid; j < m; j += 256) atomicAdd(&s_cnt[bb[j] >> 17], 1);
    __syncthreads();
    if (tid < 64) {
        int c = s_cnt[tid];
        int sc = c;
        #pragma unroll
        for (int off = 1; off < 64; off <<= 1) {
            int t = __shfl_up(sc, off, 64);
            if (tid >= off) sc += t;
        }
        s_start[tid] = sc - c;
        s_cur[tid] = sc - c;
    }
    __syncthreads();
    for (int j = tid; j < m; j += 256) {
        unsigned p = bb[j];
        int pos = atomicAdd(&s_cur[p >> 17], 1);
        s_src[pos] = (int)(p & 0x1FFFF);
    }
    __syncthreads();

    const int lane8 = tid & 7;
    const int g = tid >> 3;
    float b1r[4];
    #pragma unroll
    for (int c = 0; c < 4; ++c) b1r[c] = b1[lane8 * 4 + c];
    float vacc[4] = {0.f, 0.f, 0.f, 0.f};

    #define ACCQ(q) { float2 lo_ = __half22float2(*(__half2*)&(q).x); \
                      float2 hi_ = __half22float2(*(__half2*)&(q).y); \
                      a0 += lo_.x; a1 += lo_.y; a2 += hi_.x; a3 += hi_.y; }

    for (int local = g; local < BNODE; local += 32) {
        int n = b * BNODE + local;
        if (n >= NN) continue;
        int beg = s_start[local];
        int cn = s_cnt[local];
        int end = beg + cn;
        float a0 = 0.f, a1 = 0.f, a2 = 0.f, a3 = 0.f;
        int j = beg;
        for (; j + 8 <= end; j += 8) {
            int t0 = s_src[j+0], t1 = s_src[j+1], t2 = s_src[j+2], t3 = s_src[j+3];
            int t4 = s_src[j+4], t5 = s_src[j+5], t6 = s_src[j+6], t7 = s_src[j+7];
            uint2 q0 = *(const uint2*)(h + (size_t)t0 * 16 + lane8 * 2);
            uint2 q1 = *(const uint2*)(h + (size_t)t1 * 16 + lane8 * 2);
            uint2 q2 = *(const uint2*)(h + (size_t)t2 * 16 + lane8 * 2);
            uint2 q3 = *(const uint2*)(h + (size_t)t3 * 16 + lane8 * 2);
            uint2 q4 = *(const uint2*)(h + (size_t)t4 * 16 + lane8 * 2);
            uint2 q5 = *(const uint2*)(h + (size_t)t5 * 16 + lane8 * 2);
            uint2 q6 = *(const uint2*)(h + (size_t)t6 * 16 + lane8 * 2);
            uint2 q7 = *(const uint2*)(h + (size_t)t7 * 16 + lane8 * 2);
            ACCQ(q0) ACCQ(q1) ACCQ(q2) ACCQ(q3)
            ACCQ(q4) ACCQ(q5) ACCQ(q6) ACCQ(q7)
        }
        for (; j + 4 <= end; j += 4) {
            int t0 = s_src[j+0], t1 = s_src[j+1], t2 = s_src[j+2], t3 = s_src[j+3];
            uint2 q0 = *(const uint2*)(h + (size_t)t0 * 16 + lane8 * 2);
            uint2 q1 = *(const uint2*)(h + (size_t)t1 * 16 + lane8 * 2);
            uint2 q2 = *(const uint2*)(h + (size_t)t2 * 16 + lane8 * 2);
            uint2 q3 = *(const uint2*)(h + (size_t)t3 * 16 + lane8 * 2);
            ACCQ(q0) ACCQ(q1) ACCQ(q2) ACCQ(q3)
        }
        for (; j < end; ++j) {
            int t0 = s_src[j];
            uint2 q0 = *(const uint2*)(h + (size_t)t0 * 16 + lane8 * 2);
            ACCQ(q0)
        }
        float rs_in  = rsqrtf(fmaxf((float)cn, 1.0f));
        float rs_out = rsqrtf(fmaxf((float)deg_out[n], 1.0f));
        float alpha = rs_out * wgt[n];
        vacc[0] += alpha * fmaxf(fmaf(a0, rs_in, b1r[0]), 0.f);
        vacc[1] += alpha * fmaxf(fmaf(a1, rs_in, b1r[1]), 0.f);
        vacc[2] += alpha * fmaxf(fmaf(a2, rs_in, b1r[2]), 0.f);
        vacc[3] += alpha * fmaxf(fmaf(a3, rs_in, b1r[3]), 0.f);
    }
    #undef ACCQ

    #pragma unroll
    for (int c = 0; c < 4; ++c) {
        vacc[c] += __shfl_xor(vacc[c], 8, 64);
        vacc[c] += __shfl_xor(vacc[c], 16, 64);
        vacc[c] += __shfl_xor(vacc[c], 32, 64);
    }
    if (tid < 32) vl[tid] = 0.f;
    __syncthreads();
    if ((tid & 63) < 8) {
        #pragma unroll
        for (int c = 0; c < 4; ++c) atomicAdd(&vl[lane8 * 4 + c], vacc[c]);
    }
    __syncthreads();
    if (tid < 32) atomicAdd(&v[tid], vl[tid]);
}

// ---------------- K7: out = (v @ W2)/N + b2 ----------------
__global__ void final_kernel(const float* __restrict__ v, const float* __restrict__ W2,
                             const float* __restrict__ b2, float* __restrict__ out) {
    int c = threadIdx.x;
    if (c < CF) {
        float s = 0.f;
        #pragma unroll
        for (int k = 0; k < HF; ++k) s = fmaf(v[k], W2[k * CF + c], s);
        out[c] = s * (1.0f / NN) + b2[c];
    }
}

static inline size_t align256(size_t x) { return (x + 255) & ~(size_t)255; }

extern "C" void kernel_launch(void* const* d_in, const int* in_sizes, int n_in,
                              void* d_out, int out_size, void* d_ws, size_t ws_size,
                              hipStream_t stream) {
    const float* x   = (const float*)d_in[0];
    const int*   src = (const int*)  d_in[1];
    const int*   dst = (const int*)  d_in[2];
    const float* W1  = (const float*)d_in[3];
    const float* b1  = (const float*)d_in[4];
    const float* W2  = (const float*)d_in[5];
    const float* b2  = (const float*)d_in[6];
    float* out = (float*)d_out;

    char* base = (char*)d_ws;
    size_t off = 0;
    int*   gcur_d  = (int*)(base + off);   off = align256(off + NB1 * 4);
    int*   gcur_s  = (int*)(base + off);   off = align256(off + NB1 * 4);
    int*   gcur_f  = (int*)(base + off);   off = align256(off + NBF * 4);
    float* v       = (float*)(base + off); off = align256(off + 32 * 4);
    int*   deg_in  = (int*)(base + off);   off = align256(off + NN * 4);
    int*   deg_out = (int*)(base + off);   off = align256(off + NN * 4);
    float* wgt     = (float*)(base + off); off = align256(off + NN * 4);
    size_t zero_bytes = off;               // cursors + v + deg/wgt accumulators
    unsigned int* h      = (unsigned int*)(base + off); off = align256(off + (size_t)NN * 16 * 4);
    unsigned int* bins_d = (unsigned int*)(base + off); off = align256(off + (size_t)NB1 * CAP1 * 4);
    unsigned int* bins_s = (unsigned int*)(base + off); off = align256(off + (size_t)NB1 * CAP1 * 4);
    unsigned int* bins_f = (unsigned int*)(base + off); off = align256(off + (size_t)NBF * CAPF * 4);

    hipMemsetAsync(base, 0, zero_bytes, stream);

    const int B = 256;
    bin_coarse_kernel<<<NBLK_BIN, B, 0, stream>>>(src, dst, gcur_d, gcur_s, bins_d, bins_s);
    count_in_kernel<<<NB1 * 4, B, 0, stream>>>(bins_d, gcur_d, deg_in);
    srcside_kernel<<<NB1 * 4, B, 0, stream>>>(bins_s, gcur_s, deg_in, deg_out, wgt);
    bin_fine_kernel<<<NB1 * 16, B, 0, stream>>>(bins_d, gcur_d, gcur_f, bins_f);
    xw1_kernel<<<(NN + B - 1) / B, B, 0, stream>>>(x, W1, deg_out, h);
    gather_kernel<<<NBF, B, 0, stream>>>(bins_f, gcur_f, h, deg_out, wgt, b1, v);
    final_kernel<<<1, 64, 0, stream>>>(v, W2, b2, out);
}

// Round 9
// 128.068 us; speedup vs baseline: 4.8545x; 1.0064x over previous
//
#include <hip/hip_runtime.h>
#include <hip/hip_fp16.h>

#define NN 100000      // nodes
#define NE 1600000     // edges
#define INF 32
#define HF 32
#define CF 8

// coarse: 2048-node buckets
#define SH1 11
#define BN1 2048
#define NB1 49                           // ceil(100000/2048)
#define CAP1 36864                       // mean 32653, sigma ~180 -> +23 sigma
// fine: 64-node buckets (32 per coarse bucket)
#define BNODE 64
#define NBF (NB1 * 32)                   // 1568
#define CAPF 1280                        // mean 1024, sigma 32 -> +8 sigma
#define CHUNK 2048
#define NBLK_BIN ((NE + CHUNK - 1) / CHUNK)  // 782

// ---------------- K0: fast zero (runtime's small-fill kernel is 28 GB/s!) ----------------
__global__ void zero_kernel(uint4* __restrict__ p, int n16) {
    int i = blockIdx.x * blockDim.x + threadIdx.x;
    if (i < n16) p[i] = make_uint4(0u, 0u, 0u, 0u);
}

// ---------------- K1: dual COARSE binning (dst side + src side) ----------------
// d payload: (dst & 2047) << 17 | src ; s payload: (src & 2047) << 17 | dst
__global__ void __launch_bounds__(256) bin_coarse_kernel(
        const int* __restrict__ src, const int* __restrict__ dst,
        int* __restrict__ gcur_d, int* __restrict__ gcur_s,
        unsigned int* __restrict__ bins_d, unsigned int* __restrict__ bins_s) {
    __shared__ int cnt_d[NB1], base_d[NB1], cnt_s[NB1], base_s[NB1];
    if (threadIdx.x < NB1) { cnt_d[threadIdx.x] = 0; cnt_s[threadIdx.x] = 0; }
    __syncthreads();
    int e0 = blockIdx.x * CHUNK;
    int e1 = min(e0 + CHUNK, NE);
    for (int e = e0 + threadIdx.x; e < e1; e += 256) {
        atomicAdd(&cnt_d[dst[e] >> SH1], 1);
        atomicAdd(&cnt_s[src[e] >> SH1], 1);
    }
    __syncthreads();
    if (threadIdx.x < NB1) {
        int c = cnt_d[threadIdx.x];
        base_d[threadIdx.x] = c ? atomicAdd(&gcur_d[threadIdx.x], c) : 0;
        cnt_d[threadIdx.x] = 0;
        c = cnt_s[threadIdx.x];
        base_s[threadIdx.x] = c ? atomicAdd(&gcur_s[threadIdx.x], c) : 0;
        cnt_s[threadIdx.x] = 0;
    }
    __syncthreads();
    for (int e = e0 + threadIdx.x; e < e1; e += 256) {
        int d = dst[e], s = src[e];
        int b = d >> SH1;
        int off = base_d[b] + atomicAdd(&cnt_d[b], 1);
        if (off < CAP1)
            bins_d[(size_t)b * CAP1 + off] = ((unsigned)(d & (BN1 - 1)) << 17) | (unsigned)s;
        b = s >> SH1;
        off = base_s[b] + atomicAdd(&cnt_s[b], 1);
        if (off < CAP1)
            bins_s[(size_t)b * CAP1 + off] = ((unsigned)(s & (BN1 - 1)) << 17) | (unsigned)d;
    }
}

// ---------------- K2: deg_in from coarse dst-bins (LDS count, dense atomic merge) ----------------
__global__ void __launch_bounds__(256) count_in_kernel(
        const unsigned int* __restrict__ bins_d, const int* __restrict__ gcur_d,
        int* __restrict__ deg_in) {
    __shared__ int cnt[BN1];
    const int cb = blockIdx.x >> 2;
    const int sl = blockIdx.x & 3;
    const int tid = threadIdx.x;
    for (int i = tid; i < BN1; i += 256) cnt[i] = 0;
    __syncthreads();
    const int m = min(gcur_d[cb], CAP1);
    const int beg = (sl * m) >> 2;
    const int end = ((sl + 1) * m) >> 2;
    const unsigned int* bb = bins_d + (size_t)cb * CAP1;
    for (int j = beg + tid; j < end; j += 256) atomicAdd(&cnt[bb[j] >> 17], 1);
    __syncthreads();
    for (int i = tid; i < BN1; i += 256) {
        int c = cnt[i];
        int n = cb * BN1 + i;
        if (c && n < NN) atomicAdd(&deg_in[n], c);
    }
}

// ---------------- K3: deg_out + wgt from coarse src-bins ----------------
// wgt[n] = sum_{e: src=n} rsqrt(max(deg_in[dst[e]],1))
__global__ void __launch_bounds__(256) srcside_kernel(
        const unsigned int* __restrict__ bins_s, const int* __restrict__ gcur_s,
        const int* __restrict__ deg_in,
        int* __restrict__ deg_out, float* __restrict__ wgt) {
    __shared__ int cnt[BN1];
    __shared__ float sw[BN1];
    const int cb = blockIdx.x >> 2;
    const int sl = blockIdx.x & 3;
    const int tid = threadIdx.x;
    for (int i = tid; i < BN1; i += 256) { cnt[i] = 0; sw[i] = 0.f; }
    __syncthreads();
    const int m = min(gcur_s[cb], CAP1);
    const int beg = (sl * m) >> 2;
    const int end = ((sl + 1) * m) >> 2;
    const unsigned int* bb = bins_s + (size_t)cb * CAP1;
    for (int j = beg + tid; j < end; j += 256) {
        unsigned p = bb[j];
        int local = p >> 17;
        int d = p & 0x1FFFF;
        float riv = rsqrtf(fmaxf((float)deg_in[d], 1.0f));
        atomicAdd(&cnt[local], 1);
        atomicAdd(&sw[local], riv);
    }
    __syncthreads();
    for (int i = tid; i < BN1; i += 256) {
        int c = cnt[i];
        int n = cb * BN1 + i;
        if (c && n < NN) {
            atomicAdd(&deg_out[n], c);
            atomicAdd(&wgt[n], sw[i]);
        }
    }
}

// ---------------- K4: fine binning of dst side (full-line writes) ----------------
__global__ void __launch_bounds__(256) bin_fine_kernel(
        const unsigned int* __restrict__ bins_d, const int* __restrict__ gcur_d,
        int* __restrict__ gcur_f, unsigned int* __restrict__ bins_f) {
    __shared__ int cnt[32], base[32];
    const int cb = blockIdx.x >> 4;
    const int sl = blockIdx.x & 15;
    const int tid = threadIdx.x;
    if (tid < 32) cnt[tid] = 0;
    __syncthreads();
    const int m = min(gcur_d[cb], CAP1);
    const int beg = (sl * m) >> 4;
    const int end = ((sl + 1) * m) >> 4;
    const unsigned int* bb = bins_d + (size_t)cb * CAP1;
    for (int j = beg + tid; j < end; j += 256)
        atomicAdd(&cnt[(bb[j] >> 17) >> 6], 1);
    __syncthreads();
    if (tid < 32) {
        int c = cnt[tid];
        base[tid] = c ? atomicAdd(&gcur_f[cb * 32 + tid], c) : 0;
        cnt[tid] = 0;
    }
    __syncthreads();
    for (int j = beg + tid; j < end; j += 256) {
        unsigned p = bb[j];
        int d10 = p >> 17;
        int f = d10 >> 6;
        int off = base[f] + atomicAdd(&cnt[f], 1);
        if (off < CAPF)
            bins_f[(size_t)(cb * 32 + f) * CAPF + off] =
                ((unsigned)(d10 & 63) << 17) | (p & 0x1FFFFu);
    }
}

// ---------------- K5: h = (x @ W1) * rsqrt(deg_out), packed f16 pairs ----------------
__global__ void xw1_kernel(const float* __restrict__ x, const float* __restrict__ W1,
                           const int* __restrict__ deg_out, unsigned int* __restrict__ h) {
    __shared__ float w[INF * HF];
    for (int i = threadIdx.x; i < INF * HF; i += blockDim.x) w[i] = W1[i];
    __syncthreads();
    int n = blockIdx.x * blockDim.x + threadIdx.x;
    if (n >= NN) return;

    float xr[INF];
    const float4* xp = (const float4*)(x + (size_t)n * INF);
    #pragma unroll
    for (int i = 0; i < INF / 4; ++i) {
        float4 v = xp[i];
        xr[4*i+0] = v.x; xr[4*i+1] = v.y; xr[4*i+2] = v.z; xr[4*i+3] = v.w;
    }
    float acc[HF];
    #pragma unroll
    for (int c = 0; c < HF; ++c) acc[c] = 0.0f;
    #pragma unroll
    for (int k = 0; k < INF; ++k) {
        float xv = xr[k];
        #pragma unroll
        for (int c = 0; c < HF; ++c) acc[c] = fmaf(xv, w[k * HF + c], acc[c]);
    }
    float rs = rsqrtf(fmaxf((float)deg_out[n], 1.0f));
    unsigned int pk[HF / 2];
    #pragma unroll
    for (int i = 0; i < HF / 2; ++i) {
        __half2 p = __floats2half2_rn(acc[2*i] * rs, acc[2*i+1] * rs);
        pk[i] = *(unsigned int*)&p;
    }
    uint4* hp = (uint4*)(h + (size_t)n * (HF / 2));
    #pragma unroll
    for (int i = 0; i < 4; ++i) {
        uint4 v;
        v.x = pk[4*i+0]; v.y = pk[4*i+1]; v.z = pk[4*i+2]; v.w = pk[4*i+3];
        hp[i] = v;
    }
}

// ---------------- K6: per-fine-bucket counting sort + register-accumulate gather + fused tail ----------------
__global__ void __launch_bounds__(256) gather_kernel(
        const unsigned int* __restrict__ bins, const int* __restrict__ gcur,
        const unsigned int* __restrict__ h, const int* __restrict__ deg_out,
        const float* __restrict__ wgt, const float* __restrict__ b1,
        float* __restrict__ v) {
    __shared__ int s_cnt[BNODE];
    __shared__ int s_start[BNODE];
    __shared__ int s_cur[BNODE];
    __shared__ int s_src[CAPF];
    __shared__ float vl[32];
    const int tid = threadIdx.x;
    const int b = blockIdx.x;
    const int m = min(gcur[b], CAPF);
    const unsigned int* bb = bins + (size_t)b * CAPF;

    if (tid < BNODE) s_cnt[tid] = 0;
    __syncthreads();
    for (int j = tid; j < m; j += 256) atomicAdd(&s_cnt[bb[j] >> 17], 1);
    __syncthreads();
    if (tid < 64) {
        int c = s_cnt[tid];
        int sc = c;
        #pragma unroll
        for (int off = 1; off < 64; off <<= 1) {
            int t = __shfl_up(sc, off, 64);
            if (tid >= off) sc += t;
        }
        s_start[tid] = sc - c;
        s_cur[tid] = sc - c;
    }
    __syncthreads();
    for (int j = tid; j < m; j += 256) {
        unsigned p = bb[j];
        int pos = atomicAdd(&s_cur[p >> 17], 1);
        s_src[pos] = (int)(p & 0x1FFFF);
    }
    __syncthreads();

    const int lane8 = tid & 7;
    const int g = tid >> 3;
    float b1r[4];
    #pragma unroll
    for (int c = 0; c < 4; ++c) b1r[c] = b1[lane8 * 4 + c];
    float vacc[4] = {0.f, 0.f, 0.f, 0.f};

    #define ACCQ(q) { float2 lo_ = __half22float2(*(__half2*)&(q).x); \
                      float2 hi_ = __half22float2(*(__half2*)&(q).y); \
                      a0 += lo_.x; a1 += lo_.y; a2 += hi_.x; a3 += hi_.y; }

    for (int local = g; local < BNODE; local += 32) {
        int n = b * BNODE + local;
        if (n >= NN) continue;
        int beg = s_start[local];
        int cn = s_cnt[local];
        int end = beg + cn;
        float a0 = 0.f, a1 = 0.f, a2 = 0.f, a3 = 0.f;
        int j = beg;
        for (; j + 8 <= end; j += 8) {
            int t0 = s_src[j+0], t1 = s_src[j+1], t2 = s_src[j+2], t3 = s_src[j+3];
            int t4 = s_src[j+4], t5 = s_src[j+5], t6 = s_src[j+6], t7 = s_src[j+7];
            uint2 q0 = *(const uint2*)(h + (size_t)t0 * 16 + lane8 * 2);
            uint2 q1 = *(const uint2*)(h + (size_t)t1 * 16 + lane8 * 2);
            uint2 q2 = *(const uint2*)(h + (size_t)t2 * 16 + lane8 * 2);
            uint2 q3 = *(const uint2*)(h + (size_t)t3 * 16 + lane8 * 2);
            uint2 q4 = *(const uint2*)(h + (size_t)t4 * 16 + lane8 * 2);
            uint2 q5 = *(const uint2*)(h + (size_t)t5 * 16 + lane8 * 2);
            uint2 q6 = *(const uint2*)(h + (size_t)t6 * 16 + lane8 * 2);
            uint2 q7 = *(const uint2*)(h + (size_t)t7 * 16 + lane8 * 2);
            ACCQ(q0) ACCQ(q1) ACCQ(q2) ACCQ(q3)
            ACCQ(q4) ACCQ(q5) ACCQ(q6) ACCQ(q7)
        }
        for (; j + 4 <= end; j += 4) {
            int t0 = s_src[j+0], t1 = s_src[j+1], t2 = s_src[j+2], t3 = s_src[j+3];
            uint2 q0 = *(const uint2*)(h + (size_t)t0 * 16 + lane8 * 2);
            uint2 q1 = *(const uint2*)(h + (size_t)t1 * 16 + lane8 * 2);
            uint2 q2 = *(const uint2*)(h + (size_t)t2 * 16 + lane8 * 2);
            uint2 q3 = *(const uint2*)(h + (size_t)t3 * 16 + lane8 * 2);
            ACCQ(q0) ACCQ(q1) ACCQ(q2) ACCQ(q3)
        }
        for (; j < end; ++j) {
            int t0 = s_src[j];
            uint2 q0 = *(const uint2*)(h + (size_t)t0 * 16 + lane8 * 2);
            ACCQ(q0)
        }
        float rs_in  = rsqrtf(fmaxf((float)cn, 1.0f));
        float rs_out = rsqrtf(fmaxf((float)deg_out[n], 1.0f));
        float alpha = rs_out * wgt[n];
        vacc[0] += alpha * fmaxf(fmaf(a0, rs_in, b1r[0]), 0.f);
        vacc[1] += alpha * fmaxf(fmaf(a1, rs_in, b1r[1]), 0.f);
        vacc[2] += alpha * fmaxf(fmaf(a2, rs_in, b1r[2]), 0.f);
        vacc[3] += alpha * fmaxf(fmaf(a3, rs_in, b1r[3]), 0.f);
    }
    #undef ACCQ

    #pragma unroll
    for (int c = 0; c < 4; ++c) {
        vacc[c] += __shfl_xor(vacc[c], 8, 64);
        vacc[c] += __shfl_xor(vacc[c], 16, 64);
        vacc[c] += __shfl_xor(vacc[c], 32, 64);
    }
    if (tid < 32) vl[tid] = 0.f;
    __syncthreads();
    if ((tid & 63) < 8) {
        #pragma unroll
        for (int c = 0; c < 4; ++c) atomicAdd(&vl[lane8 * 4 + c], vacc[c]);
    }
    __syncthreads();
    if (tid < 32) atomicAdd(&v[tid], vl[tid]);
}

// ---------------- K7: out = (v @ W2)/N + b2 ----------------
__global__ void final_kernel(const float* __restrict__ v, const float* __restrict__ W2,
                             const float* __restrict__ b2, float* __restrict__ out) {
    int c = threadIdx.x;
    if (c < CF) {
        float s = 0.f;
        #pragma unroll
        for (int k = 0; k < HF; ++k) s = fmaf(v[k], W2[k * CF + c], s);
        out[c] = s * (1.0f / NN) + b2[c];
    }
}

static inline size_t align256(size_t x) { return (x + 255) & ~(size_t)255; }

extern "C" void kernel_launch(void* const* d_in, const int* in_sizes, int n_in,
                              void* d_out, int out_size, void* d_ws, size_t ws_size,
                              hipStream_t stream) {
    const float* x   = (const float*)d_in[0];
    const int*   src = (const int*)  d_in[1];
    const int*   dst = (const int*)  d_in[2];
    const float* W1  = (const float*)d_in[3];
    const float* b1  = (const float*)d_in[4];
    const float* W2  = (const float*)d_in[5];
    const float* b2  = (const float*)d_in[6];
    float* out = (float*)d_out;

    char* base = (char*)d_ws;
    size_t off = 0;
    int*   gcur_d  = (int*)(base + off);   off = align256(off + NB1 * 4);
    int*   gcur_s  = (int*)(base + off);   off = align256(off + NB1 * 4);
    int*   gcur_f  = (int*)(base + off);   off = align256(off + NBF * 4);
    float* v       = (float*)(base + off); off = align256(off + 32 * 4);
    int*   deg_in  = (int*)(base + off);   off = align256(off + NN * 4);
    int*   deg_out = (int*)(base + off);   off = align256(off + NN * 4);
    float* wgt     = (float*)(base + off); off = align256(off + NN * 4);
    size_t zero_bytes = off;               // cursors + v + deg/wgt accumulators (~1.2 MB)
    unsigned int* h      = (unsigned int*)(base + off); off = align256(off + (size_t)NN * 16 * 4);
    unsigned int* bins_d = (unsigned int*)(base + off); off = align256(off + (size_t)NB1 * CAP1 * 4);
    unsigned int* bins_s = (unsigned int*)(base + off); off = align256(off + (size_t)NB1 * CAP1 * 4);
    unsigned int* bins_f = (unsigned int*)(base + off); off = align256(off + (size_t)NBF * CAPF * 4);

    const int B = 256;
    // custom zero: runtime's fillBuffer ran at 28 GB/s (43 us) for this 1.2 MB
    int n16 = (int)(zero_bytes / 16);
    zero_kernel<<<(n16 + B - 1) / B, B, 0, stream>>>((uint4*)base, n16);

    bin_coarse_kernel<<<NBLK_BIN, B, 0, stream>>>(src, dst, gcur_d, gcur_s, bins_d, bins_s);
    count_in_kernel<<<NB1 * 4, B, 0, stream>>>(bins_d, gcur_d, deg_in);
    srcside_kernel<<<NB1 * 4, B, 0, stream>>>(bins_s, gcur_s, deg_in, deg_out, wgt);
    bin_fine_kernel<<<NB1 * 16, B, 0, stream>>>(bins_d, gcur_d, gcur_f, bins_f);
    xw1_kernel<<<(NN + B - 1) / B, B, 0, stream>>>(x, W1, deg_out, h);
    gather_kernel<<<NBF, B, 0, stream>>>(bins_f, gcur_f, h, deg_out, wgt, b1, v);
    final_kernel<<<1, 64, 0, stream>>>(v, W2, b2, out);
}